// Round 17
// baseline (1082.626 us; speedup 1.0000x reference)
//
#include <hip/hip_runtime.h>

typedef unsigned short u16;
typedef unsigned int   u32;
typedef __attribute__((ext_vector_type(8))) short short8;   // 8 bf16 MFMA A/B frag
typedef __attribute__((ext_vector_type(4))) float f32x4;
typedef __attribute__((ext_vector_type(4))) u16   u16x4;

#define GLOAD16(gp, lp) __builtin_amdgcn_global_load_lds( \
    (const __attribute__((address_space(1))) void*)(gp),   \
    (__attribute__((address_space(3))) void*)(lp), 16, 0, 0)

__device__ __forceinline__ float bf2f(u16 u) {
  union { u32 i; float f; } v; v.i = ((u32)u) << 16; return v.f;
}
__device__ __forceinline__ u16 f2bf(float f) {
  union { float f; u32 i; } v; v.f = f;
  return (u16)((v.i + 0x7fffu + ((v.i >> 16) & 1u)) >> 16);
}

// Problem constants
#define TTOK 8192
#define SLEN 1024
#define NBATCH 8
#define NHQ 32
#define NKVH 8
#define HDIM 128
#define QKVW 6144
#define HID 4096

// ---------------- fused dual cache copy (k and v in one launch) ----------------
__global__ void ap_copy2(const f32x4* __restrict__ ks, f32x4* __restrict__ kd,
                         const f32x4* __restrict__ vs, f32x4* __restrict__ vd, int n4) {
  int stride = gridDim.x * 256;
  for (int i = blockIdx.x * 256 + threadIdx.x; i < 2 * n4; i += stride) {
    if (i < n4) kd[i] = ks[i];
    else        vd[i - n4] = vs[i - n4];
  }
}

// ---------------- x f32 -> bf16 ----------------
__global__ void ap_convx(const float* __restrict__ x, u16* __restrict__ xb) {
  size_t e = ((size_t)blockIdx.x * 256 + threadIdx.x) * 8;
  f32x4 a = *(const f32x4*)(x + e);
  f32x4 b = *(const f32x4*)(x + e + 4);
  short8 o;
  o[0]=(short)f2bf(a[0]); o[1]=(short)f2bf(a[1]); o[2]=(short)f2bf(a[2]); o[3]=(short)f2bf(a[3]);
  o[4]=(short)f2bf(b[0]); o[5]=(short)f2bf(b[1]); o[6]=(short)f2bf(b[2]); o[7]=(short)f2bf(b[3]);
  *(short8*)(xb + e) = o;
}

// ---------------- transpose-cast: src (K,N) f32 -> dst (N,K) bf16 ----------------
__global__ __launch_bounds__(256) void ap_tconv(const float* __restrict__ src,
                                                u16* __restrict__ dst, int K, int N) {
  __shared__ u16 tile[64][68];
  int nt = N >> 6;
  int tn = blockIdx.x % nt, tk = blockIdx.x / nt;
  int rr = threadIdx.x >> 4, cc = (threadIdx.x & 15) * 4;
#pragma unroll
  for (int i = 0; i < 4; ++i) {
    int row = i * 16 + rr;
    f32x4 v = *(const f32x4*)(src + (size_t)(tk * 64 + row) * N + tn * 64 + cc);
#pragma unroll
    for (int j = 0; j < 4; ++j) tile[row][cc + j] = f2bf(v[j]);
  }
  __syncthreads();
#pragma unroll
  for (int i = 0; i < 4; ++i) {
    int orow = i * 16 + rr;
    u16x4 o;
#pragma unroll
    for (int j = 0; j < 4; ++j) o[j] = tile[cc + j][orow];
    *(u16x4*)(dst + (size_t)(tn * 64 + orow) * K + tk * 64 + cc) = o;
  }
}

// ---------------- 256x256 GEMM, 16 waves (1024 thr), 16x16x32 MFMA ----------------
// R14 config — empirical optimum of 7 explored structures (1033 TF):
// double-buffered LDS, two clusters per K-tile {8 ds_read -> lgkm(0) -> 16
// MFMA}, header staging with counted vmcnt(4). 60 VGPR, no spill.
__device__ __forceinline__ void ap_stage1k(const u16* __restrict__ g, int ldk,
                                           u16* __restrict__ l, int tid) {
#pragma unroll
  for (int i = 0; i < 2; ++i) {
    int ci = i * 1024 + tid;
    int r = ci >> 3;
    int cb = (ci & 7) * 16;
    int c = (cb ^ ((r & 7) << 4)) >> 1;
    GLOAD16(g + (size_t)r * ldk + c, l + ci * 8);
  }
}

__device__ __forceinline__ short8 ds_frag(const u16* base, int row, int kbyte, int swz) {
  return *(const short8*)((const char*)base + row * 128 + (kbyte ^ swz));
}

template <int OUT_BF16, int HAS_BIAS>
__global__ __launch_bounds__(1024) void ap_gemmw(const u16* __restrict__ A,
                                                 const u16* __restrict__ BT,
                                                 const float* __restrict__ bias,
                                                 void* __restrict__ Cout,
                                                 int M, int N, int K, int nbn) {
  __shared__ u16 sA[2][16384];
  __shared__ u16 sB[2][16384];
  const int tid = threadIdx.x;
  const int wave = tid >> 6, l = tid & 63, l16 = l & 15, lq = l >> 4;
  const int wr = wave >> 2, wc = wave & 3;
  const int swz = (l16 & 7) << 4;

  // XCD-bijective block swizzle (grid % 8 == 0)
  const int nwg = nbn * (M >> 8);
  const int cpx = nwg >> 3;
  const int wg = (blockIdx.x & 7) * cpx + (blockIdx.x >> 3);
  const int bm = wg / nbn, bn = wg % nbn;

  f32x4 acc[4][4];
  f32x4 zv = {0.f, 0.f, 0.f, 0.f};
#pragma unroll
  for (int mf = 0; mf < 4; ++mf)
#pragma unroll
    for (int nf = 0; nf < 4; ++nf) acc[mf][nf] = zv;

  const u16* Abase = A + (size_t)(bm * 256) * K;
  const u16* Bbase = BT + (size_t)(bn * 256) * K;
  const int NT = K >> 6;

  // prologue: tile 0 (4 loads/thread in flight)
  ap_stage1k(Abase, K, sA[0], tid);
  ap_stage1k(Bbase, K, sB[0], tid);

  for (int kt = 0; kt < NT; ++kt) {
    const u16* sAc = sA[kt & 1];
    const u16* sBc = sB[kt & 1];
    const bool pf = (kt + 1 < NT);

    // header: stage next tile (4 loads); counted wait on current's 4; publish
    if (pf) {
      ap_stage1k(Abase + (kt + 1) * 64, K, sA[(kt + 1) & 1], tid);
      ap_stage1k(Bbase + (kt + 1) * 64, K, sB[(kt + 1) & 1], tid);
      asm volatile("s_waitcnt vmcnt(4)" ::: "memory");   // tile kt landed
    } else {
      asm volatile("s_waitcnt vmcnt(0)" ::: "memory");
    }
    __builtin_amdgcn_s_barrier();
    __builtin_amdgcn_sched_barrier(0);

    // cluster 0 (ks=0): 8 reads -> 16 independent MFMA
    {
      short8 bf_[4], af_[4];
#pragma unroll
      for (int nf = 0; nf < 4; ++nf)
        bf_[nf] = ds_frag(sBc, wc * 64 + nf * 16 + l16, lq * 16, swz);
#pragma unroll
      for (int mf = 0; mf < 4; ++mf)
        af_[mf] = ds_frag(sAc, wr * 64 + mf * 16 + l16, lq * 16, swz);
      asm volatile("s_waitcnt lgkmcnt(0)" ::: "memory");
      __builtin_amdgcn_sched_barrier(0);
      __builtin_amdgcn_s_setprio(1);
#pragma unroll
      for (int mf = 0; mf < 4; ++mf)
#pragma unroll
        for (int nf = 0; nf < 4; ++nf)
          acc[mf][nf] = __builtin_amdgcn_mfma_f32_16x16x32_bf16(
              af_[mf], bf_[nf], acc[mf][nf], 0, 0, 0);
      __builtin_amdgcn_s_setprio(0);
    }
    // cluster 1 (ks=1): reads returned -> release barrier BEFORE final MFMAs
    {
      short8 bf_[4], af_[4];
#pragma unroll
      for (int nf = 0; nf < 4; ++nf)
        bf_[nf] = ds_frag(sBc, wc * 64 + nf * 16 + l16, 64 + lq * 16, swz);
#pragma unroll
      for (int mf = 0; mf < 4; ++mf)
        af_[mf] = ds_frag(sAc, wr * 64 + mf * 16 + l16, 64 + lq * 16, swz);
      asm volatile("s_waitcnt lgkmcnt(0)" ::: "memory");
      __builtin_amdgcn_sched_barrier(0);
      __builtin_amdgcn_s_barrier();   // all tile-kt LDS reads retired block-wide
      __builtin_amdgcn_s_setprio(1);
#pragma unroll
      for (int mf = 0; mf < 4; ++mf)
#pragma unroll
        for (int nf = 0; nf < 4; ++nf)
          acc[mf][nf] = __builtin_amdgcn_mfma_f32_16x16x32_bf16(
              af_[mf], bf_[nf], acc[mf][nf], 0, 0, 0);
      __builtin_amdgcn_s_setprio(0);
    }
  }

  // epilogue: 16x16 C/D layout col=lane&15, row=(lane>>4)*4+reg
#pragma unroll
  for (int mf = 0; mf < 4; ++mf)
#pragma unroll
    for (int nf = 0; nf < 4; ++nf) {
      int col = bn * 256 + wc * 64 + nf * 16 + l16;
      float bv = HAS_BIAS ? bias[col] : 0.f;
#pragma unroll
      for (int r = 0; r < 4; ++r) {
        int row = bm * 256 + wr * 64 + mf * 16 + lq * 4 + r;
        float v = acc[mf][nf][r] + bv;
        if (OUT_BF16)
          ((u16*)Cout)[(size_t)row * N + col] = f2bf(v);
        else
          ((float*)Cout)[(size_t)row * N + col] = v;
      }
    }
}

// ---------------- RoPE in-place on q,k + k-cache write ----------------
__global__ __launch_bounds__(256) void ap_rope(u16* __restrict__ qkv,
                                               const int* __restrict__ pos_list,
                                               const int* __restrict__ slot_mapping,
                                               float* __restrict__ kc) {
  int gid = blockIdx.x * 4 + (threadIdx.x >> 6);
  int i = threadIdx.x & 63;
  int t = gid / 40, head = gid % 40;
  float pos = (float)pos_list[t];
  float inv = expf(-(float)i * 0.14391156516151135f);
  float ang = pos * inv;
  float cs = cosf(ang), sn = sinf(ang);
  int cb = (head < 32) ? head * 128 : 4096 + (head - 32) * 128;
  u16* p = qkv + (size_t)t * QKVW + cb;
  float t1 = bf2f(p[i]), t2 = bf2f(p[i + 64]);
  float o1 = t1 * cs - t2 * sn;
  float o2 = t2 * cs + t1 * sn;
  p[i] = f2bf(o1);
  p[i + 64] = f2bf(o2);
  if (head >= 32) {
    int slot = slot_mapping[t];
    float* kp = kc + (size_t)slot * (NKVH * HDIM) + (head - 32) * 128;
    kp[i] = o1;
    kp[i + 64] = o2;
  }
}

// ---------------- v -> V^T (per b,h) bf16 + v_cache scatter (fused) ----------------
__global__ __launch_bounds__(256) void ap_vtrans2(const u16* __restrict__ qkv,
                                                  const int* __restrict__ slot_mapping,
                                                  float* __restrict__ vc,
                                                  u16* __restrict__ Vt) {
  __shared__ u16 tile[64][68];
  int bid = blockIdx.x;
  int hdt = bid & 1, st = (bid >> 1) & 15, head = bid >> 5;
  int b = head >> 3, h = head & 7;
  int rr = threadIdx.x >> 4, cc = (threadIdx.x & 15) * 4;
#pragma unroll
  for (int i = 0; i < 4; ++i) {
    int s = i * 16 + rr;
    int t = b * 1024 + st * 64 + s;
    u16x4 v = *(const u16x4*)(qkv + (size_t)t * QKVW + 5120 + h * 128 + hdt * 64 + cc);
#pragma unroll
    for (int j = 0; j < 4; ++j) tile[s][cc + j] = v[j];
    int slot = slot_mapping[t];
    f32x4 o;
#pragma unroll
    for (int j = 0; j < 4; ++j) o[j] = bf2f(v[j]);
    *(f32x4*)(vc + (size_t)slot * 1024 + h * 128 + hdt * 64 + cc) = o;
  }
  __syncthreads();
#pragma unroll
  for (int i = 0; i < 4; ++i) {
    int hd = i * 16 + rr;
    u16x4 o;
#pragma unroll
    for (int j = 0; j < 4; ++j) o[j] = tile[cc + j][hd];
    *(u16x4*)(Vt + (size_t)head * (HDIM * SLEN) + (size_t)(hdt * 64 + hd) * SLEN +
              st * 64 + cc) = o;
  }
}

// ---------------- flash attention v8: + masked-half-tile skip ----------------
// block = (b, kvh, 64 q-rows); 8 waves = 4 GQA heads x 2 q-halves.
// Lower-half waves' final tile (kv0 == q0): kv columns 32..63 are entirely
// causal-masked -> skip their QK^T MFMAs, exps, sP writes, and PV ks=1
// (wave-uniform branch, no divergence; sP cols 32-63 never read).
__global__ __launch_bounds__(512) void ap_attn8(const u16* __restrict__ qkv,
                                                const u16* __restrict__ Vt,
                                                u16* __restrict__ O) {
  __shared__ u16 sK[64 * 136];      // K tile (kv,hd), stride 136
  __shared__ u16 sV[128 * 72];      // V^T tile (hd,kv), stride 72
  __shared__ u16 sP[8 * 32 * 72];   // per-wave P (q,kv), stride 72
  const int tid = threadIdx.x;
  const int wave = tid >> 6, l = tid & 63, l16 = l & 15, lq = l >> 4;
  const int bid = blockIdx.x;
  const int qt = 15 - (bid & 15);   // heavy blocks first
  const int kvh = (bid >> 4) & 7;
  const int b = bid >> 7;
  const int qh = kvh * 4 + (wave & 3);
  const int q0 = qt * 64 + (wave >> 2) * 32;
  const int head = b * 8 + kvh;
  const float SC2 = 0.12751649736230717f;  // 128^-0.5 * log2(e)

  short8 qf[2][4];
#pragma unroll
  for (int m = 0; m < 2; ++m)
#pragma unroll
    for (int kd = 0; kd < 4; ++kd) {
      size_t t = (size_t)(b * 1024 + q0 + m * 16 + l16);
      qf[m][kd] = *(const short8*)(qkv + t * QKVW + qh * 128 + kd * 32 + lq * 8);
    }

  u16* sPw = sP + wave * 2304;
  f32x4 zv = {0.f, 0.f, 0.f, 0.f};
  f32x4 oacc[2][8];
#pragma unroll
  for (int m = 0; m < 2; ++m)
#pragma unroll
    for (int n = 0; n < 8; ++n) oacc[m][n] = zv;
  float mrun[2][4], lrun[2][4];   // lrun = per-lane partial row sums
#pragma unroll
  for (int m = 0; m < 2; ++m)
#pragma unroll
    for (int r = 0; r < 4; ++r) { mrun[m][r] = -1e30f; lrun[m][r] = 0.f; }

  const int ntiles = qt + 1;
  for (int kt = 0; kt < ntiles; ++kt) {
    const int kv0 = kt * 64;
    const bool half = (kv0 >= q0);  // nf 2,3 fully masked (lower wave, last tile)
#pragma unroll
    for (int i = 0; i < 2; ++i) {
      int ci = i * 512 + tid;
      int kr = ci >> 4, ko = (ci & 15) * 8;
      short8 v = *(const short8*)(qkv + (size_t)(b * 1024 + kv0 + kr) * QKVW + 4096 +
                                  kvh * 128 + ko);
      *(short8*)&sK[kr * 136 + ko] = v;
    }
#pragma unroll
    for (int i = 0; i < 2; ++i) {
      int ci = i * 512 + tid;
      int hd = ci >> 3, ko = (ci & 7) * 8;
      short8 v = *(const short8*)(Vt + (size_t)head * (HDIM * SLEN) + (size_t)hd * SLEN +
                                  kv0 + ko);
      *(short8*)&sV[hd * 72 + ko] = v;
    }
    __syncthreads();

    f32x4 sacc[2][4];
#pragma unroll
    for (int m = 0; m < 2; ++m)
#pragma unroll
      for (int nf = 0; nf < 4; ++nf) sacc[m][nf] = zv;
#pragma unroll
    for (int kd = 0; kd < 4; ++kd) {
      short8 kf[4];
#pragma unroll
      for (int nf = 0; nf < 4; ++nf)
        if (!(nf >= 2 && half))
          kf[nf] = *(const short8*)&sK[(nf * 16 + l16) * 136 + kd * 32 + lq * 8];
#pragma unroll
      for (int m = 0; m < 2; ++m)
#pragma unroll
        for (int nf = 0; nf < 4; ++nf)
          if (!(nf >= 2 && half))
            sacc[m][nf] = __builtin_amdgcn_mfma_f32_16x16x32_bf16(qf[m][kd], kf[nf], sacc[m][nf], 0, 0, 0);
    }
    if (kv0 + 63 > q0) {
#pragma unroll
      for (int m = 0; m < 2; ++m)
#pragma unroll
        for (int nf = 0; nf < 4; ++nf) {
          if (nf >= 2 && half) continue;
          int kv = kv0 + nf * 16 + l16;
#pragma unroll
          for (int r = 0; r < 4; ++r) {
            int q = q0 + m * 16 + lq * 4 + r;
            if (kv > q) sacc[m][nf][r] = -1e30f;
          }
        }
    }
    // ---- defer-max softmax with shuffle-free fast path ----
    float lmax[2][4];
    bool need = false;
#pragma unroll
    for (int m = 0; m < 2; ++m)
#pragma unroll
      for (int r = 0; r < 4; ++r) {
        float mx01 = fmaxf(sacc[m][0][r], sacc[m][1][r]);
        lmax[m][r] = half ? mx01 : fmaxf(mx01, fmaxf(sacc[m][2][r], sacc[m][3][r]));
        need = need || ((lmax[m][r] - mrun[m][r]) * SC2 > 8.f);
      }
    if (!__all(!need)) {
#pragma unroll
      for (int m = 0; m < 2; ++m)
#pragma unroll
        for (int r = 0; r < 4; ++r) {
          float mx = lmax[m][r];
#pragma unroll
          for (int off = 8; off; off >>= 1) mx = fmaxf(mx, __shfl_xor(mx, off));
          if ((mx - mrun[m][r]) * SC2 > 8.f) {
            float sc = exp2f((mrun[m][r] - mx) * SC2);
            mrun[m][r] = mx;
            lrun[m][r] *= sc;
#pragma unroll
            for (int n = 0; n < 8; ++n) oacc[m][n][r] *= sc;
          }
        }
    }
#pragma unroll
    for (int m = 0; m < 2; ++m)
#pragma unroll
      for (int r = 0; r < 4; ++r) {
        float mn = mrun[m][r];
        float p0 = exp2f((sacc[m][0][r] - mn) * SC2);
        float p1 = exp2f((sacc[m][1][r] - mn) * SC2);
        int prow = (m * 16 + lq * 4 + r) * 72;
        sPw[prow + l16]      = f2bf(p0);
        sPw[prow + 16 + l16] = f2bf(p1);
        float rs = p0 + p1;
        if (!half) {
          float p2 = exp2f((sacc[m][2][r] - mn) * SC2);
          float p3 = exp2f((sacc[m][3][r] - mn) * SC2);
          sPw[prow + 32 + l16] = f2bf(p2);
          sPw[prow + 48 + l16] = f2bf(p3);
          rs += p2 + p3;
        }
        lrun[m][r] += rs;
      }
    short8 pa[2][2];
#pragma unroll
    for (int m = 0; m < 2; ++m)
#pragma unroll
      for (int ks = 0; ks < 2; ++ks)
        if (!(ks == 1 && half))
          pa[m][ks] = *(const short8*)&sPw[(m * 16 + l16) * 72 + ks * 32 + lq * 8];
#pragma unroll
    for (int n = 0; n < 8; ++n) {
#pragma unroll
      for (int ks = 0; ks < 2; ++ks) {
        if (ks == 1 && half) continue;
        short8 vb = *(const short8*)&sV[(n * 16 + l16) * 72 + ks * 32 + lq * 8];
#pragma unroll
        for (int m = 0; m < 2; ++m)
          oacc[m][n] = __builtin_amdgcn_mfma_f32_16x16x32_bf16(pa[m][ks], vb, oacc[m][n], 0, 0, 0);
      }
    }
    __syncthreads();
  }
  // epilogue: reduce per-lane lrun partials across the 16-lane group, store
#pragma unroll
  for (int m = 0; m < 2; ++m)
#pragma unroll
    for (int r = 0; r < 4; ++r) {
      float s = lrun[m][r];
#pragma unroll
      for (int off = 8; off; off >>= 1) s += __shfl_xor(s, off);
      float inv = 1.f / s;
      size_t t = (size_t)(b * 1024 + q0 + m * 16 + lq * 4 + r);
#pragma unroll
      for (int n = 0; n < 8; ++n)
        O[t * (size_t)HID + qh * 128 + n * 16 + l16] = f2bf(oacc[m][n][r] * inv);
    }
}

// ---------------- launch ----------------
extern "C" void kernel_launch(void* const* d_in, const int* in_sizes, int n_in,
                              void* d_out, int out_size, void* d_ws, size_t ws_size,
                              hipStream_t stream) {
  const float* x = (const float*)d_in[0];
  const float* wqkv = (const float*)d_in[1];
  const float* bqkv = (const float*)d_in[2];
  const float* wo = (const float*)d_in[3];
  const int* pos_list = (const int*)d_in[4];
  const int* slot_mapping = (const int*)d_in[5];
  const float* k_cache = (const float*)d_in[6];
  const float* v_cache = (const float*)d_in[7];

  float* out = (float*)d_out;
  float* kc = out + (size_t)33554432;
  float* vc = kc + (size_t)16777216;

  char* ws = (char*)d_ws;
  u16* xb    = (u16*)(ws);
  u16* wqkvT = (u16*)(ws + 67108864);
  u16* woT   = (u16*)(ws + 117440512);
  u16* qkvb  = (u16*)(ws + 150994944);
  u16* Vt    = (u16*)(ws + 251658240);
  u16* attnO = xb;

  ap_copy2<<<8192, 256, 0, stream>>>((const f32x4*)k_cache, (f32x4*)kc,
                                     (const f32x4*)v_cache, (f32x4*)vc, 4194304);
  ap_convx<<<16384, 256, 0, stream>>>(x, xb);
  ap_tconv<<<6144, 256, 0, stream>>>(wqkv, wqkvT, 4096, 6144);
  ap_tconv<<<4096, 256, 0, stream>>>(wo, woT, 4096, 4096);
  ap_gemmw<1, 1><<<768, 1024, 0, stream>>>(xb, wqkvT, bqkv, qkvb, 8192, 6144, 4096, 24);
  ap_rope<<<81920, 256, 0, stream>>>(qkvb, pos_list, slot_mapping, kc);
  ap_vtrans2<<<2048, 256, 0, stream>>>(qkvb, slot_mapping, vc, Vt);
  ap_attn8<<<1024, 512, 0, stream>>>(qkvb, Vt, attnO);
  ap_gemmw<0, 0><<<512, 1024, 0, stream>>>(attnO, woT, nullptr, out, 8192, 4096, 4096, 16);
}

// Round 18
// 1061.402 us; speedup vs baseline: 1.0200x; 1.0200x over previous
//
#include <hip/hip_runtime.h>

typedef unsigned short u16;
typedef unsigned int   u32;
typedef __attribute__((ext_vector_type(8))) short short8;   // 8 bf16 MFMA A/B frag
typedef __attribute__((ext_vector_type(4))) float f32x4;
typedef __attribute__((ext_vector_type(4))) u16   u16x4;

#define GLOAD16(gp, lp) __builtin_amdgcn_global_load_lds( \
    (const __attribute__((address_space(1))) void*)(gp),   \
    (__attribute__((address_space(3))) void*)(lp), 16, 0, 0)

__device__ __forceinline__ float bf2f(u16 u) {
  union { u32 i; float f; } v; v.i = ((u32)u) << 16; return v.f;
}
__device__ __forceinline__ u16 f2bf(float f) {
  union { float f; u32 i; } v; v.f = f;
  return (u16)((v.i + 0x7fffu + ((v.i >> 16) & 1u)) >> 16);
}

// Problem constants
#define TTOK 8192
#define SLEN 1024
#define NBATCH 8
#define NHQ 32
#define NKVH 8
#define HDIM 128
#define QKVW 6144
#define HID 4096

// ---------------- fused dual cache copy (k and v in one launch) ----------------
__global__ void ap_copy2(const f32x4* __restrict__ ks, f32x4* __restrict__ kd,
                         const f32x4* __restrict__ vs, f32x4* __restrict__ vd, int n4) {
  int stride = gridDim.x * 256;
  for (int i = blockIdx.x * 256 + threadIdx.x; i < 2 * n4; i += stride) {
    if (i < n4) kd[i] = ks[i];
    else        vd[i - n4] = vs[i - n4];
  }
}

// ---------------- x f32 -> bf16 ----------------
__global__ void ap_convx(const float* __restrict__ x, u16* __restrict__ xb) {
  size_t e = ((size_t)blockIdx.x * 256 + threadIdx.x) * 8;
  f32x4 a = *(const f32x4*)(x + e);
  f32x4 b = *(const f32x4*)(x + e + 4);
  short8 o;
  o[0]=(short)f2bf(a[0]); o[1]=(short)f2bf(a[1]); o[2]=(short)f2bf(a[2]); o[3]=(short)f2bf(a[3]);
  o[4]=(short)f2bf(b[0]); o[5]=(short)f2bf(b[1]); o[6]=(short)f2bf(b[2]); o[7]=(short)f2bf(b[3]);
  *(short8*)(xb + e) = o;
}

// ---------------- transpose-cast: src (K,N) f32 -> dst (N,K) bf16 ----------------
__global__ __launch_bounds__(256) void ap_tconv(const float* __restrict__ src,
                                                u16* __restrict__ dst, int K, int N) {
  __shared__ u16 tile[64][68];
  int nt = N >> 6;
  int tn = blockIdx.x % nt, tk = blockIdx.x / nt;
  int rr = threadIdx.x >> 4, cc = (threadIdx.x & 15) * 4;
#pragma unroll
  for (int i = 0; i < 4; ++i) {
    int row = i * 16 + rr;
    f32x4 v = *(const f32x4*)(src + (size_t)(tk * 64 + row) * N + tn * 64 + cc);
#pragma unroll
    for (int j = 0; j < 4; ++j) tile[row][cc + j] = f2bf(v[j]);
  }
  __syncthreads();
#pragma unroll
  for (int i = 0; i < 4; ++i) {
    int orow = i * 16 + rr;
    u16x4 o;
#pragma unroll
    for (int j = 0; j < 4; ++j) o[j] = tile[cc + j][orow];
    *(u16x4*)(dst + (size_t)(tn * 64 + orow) * K + tk * 64 + cc) = o;
  }
}

// ---------------- 256x256 GEMM, 16 waves (1024 thr), 16x16x32 MFMA ----------------
// R14 config — empirical optimum of 9 explored structures (1033 TF):
// double-buffered LDS, two clusters per K-tile {8 ds_read -> lgkm(0) -> 16
// MFMA}, header staging with counted vmcnt(4). 60 VGPR, no spill.
__device__ __forceinline__ void ap_stage1k(const u16* __restrict__ g, int ldk,
                                           u16* __restrict__ l, int tid) {
#pragma unroll
  for (int i = 0; i < 2; ++i) {
    int ci = i * 1024 + tid;
    int r = ci >> 3;
    int cb = (ci & 7) * 16;
    int c = (cb ^ ((r & 7) << 4)) >> 1;
    GLOAD16(g + (size_t)r * ldk + c, l + ci * 8);
  }
}

__device__ __forceinline__ short8 ds_frag(const u16* base, int row, int kbyte, int swz) {
  return *(const short8*)((const char*)base + row * 128 + (kbyte ^ swz));
}

template <int OUT_BF16, int HAS_BIAS>
__global__ __launch_bounds__(1024) void ap_gemmw(const u16* __restrict__ A,
                                                 const u16* __restrict__ BT,
                                                 const float* __restrict__ bias,
                                                 void* __restrict__ Cout,
                                                 int M, int N, int K, int nbn) {
  __shared__ u16 sA[2][16384];
  __shared__ u16 sB[2][16384];
  const int tid = threadIdx.x;
  const int wave = tid >> 6, l = tid & 63, l16 = l & 15, lq = l >> 4;
  const int wr = wave >> 2, wc = wave & 3;
  const int swz = (l16 & 7) << 4;

  // XCD-bijective block swizzle (grid % 8 == 0)
  const int nwg = nbn * (M >> 8);
  const int cpx = nwg >> 3;
  const int wg = (blockIdx.x & 7) * cpx + (blockIdx.x >> 3);
  const int bm = wg / nbn, bn = wg % nbn;

  f32x4 acc[4][4];
  f32x4 zv = {0.f, 0.f, 0.f, 0.f};
#pragma unroll
  for (int mf = 0; mf < 4; ++mf)
#pragma unroll
    for (int nf = 0; nf < 4; ++nf) acc[mf][nf] = zv;

  const u16* Abase = A + (size_t)(bm * 256) * K;
  const u16* Bbase = BT + (size_t)(bn * 256) * K;
  const int NT = K >> 6;

  // prologue: tile 0 (4 loads/thread in flight)
  ap_stage1k(Abase, K, sA[0], tid);
  ap_stage1k(Bbase, K, sB[0], tid);

  for (int kt = 0; kt < NT; ++kt) {
    const u16* sAc = sA[kt & 1];
    const u16* sBc = sB[kt & 1];
    const bool pf = (kt + 1 < NT);

    // header: stage next tile (4 loads); counted wait on current's 4; publish
    if (pf) {
      ap_stage1k(Abase + (kt + 1) * 64, K, sA[(kt + 1) & 1], tid);
      ap_stage1k(Bbase + (kt + 1) * 64, K, sB[(kt + 1) & 1], tid);
      asm volatile("s_waitcnt vmcnt(4)" ::: "memory");   // tile kt landed
    } else {
      asm volatile("s_waitcnt vmcnt(0)" ::: "memory");
    }
    __builtin_amdgcn_s_barrier();
    __builtin_amdgcn_sched_barrier(0);

    // cluster 0 (ks=0): 8 reads -> 16 independent MFMA
    {
      short8 bf_[4], af_[4];
#pragma unroll
      for (int nf = 0; nf < 4; ++nf)
        bf_[nf] = ds_frag(sBc, wc * 64 + nf * 16 + l16, lq * 16, swz);
#pragma unroll
      for (int mf = 0; mf < 4; ++mf)
        af_[mf] = ds_frag(sAc, wr * 64 + mf * 16 + l16, lq * 16, swz);
      asm volatile("s_waitcnt lgkmcnt(0)" ::: "memory");
      __builtin_amdgcn_sched_barrier(0);
      __builtin_amdgcn_s_setprio(1);
#pragma unroll
      for (int mf = 0; mf < 4; ++mf)
#pragma unroll
        for (int nf = 0; nf < 4; ++nf)
          acc[mf][nf] = __builtin_amdgcn_mfma_f32_16x16x32_bf16(
              af_[mf], bf_[nf], acc[mf][nf], 0, 0, 0);
      __builtin_amdgcn_s_setprio(0);
    }
    // cluster 1 (ks=1): reads returned -> release barrier BEFORE final MFMAs
    {
      short8 bf_[4], af_[4];
#pragma unroll
      for (int nf = 0; nf < 4; ++nf)
        bf_[nf] = ds_frag(sBc, wc * 64 + nf * 16 + l16, 64 + lq * 16, swz);
#pragma unroll
      for (int mf = 0; mf < 4; ++mf)
        af_[mf] = ds_frag(sAc, wr * 64 + mf * 16 + l16, 64 + lq * 16, swz);
      asm volatile("s_waitcnt lgkmcnt(0)" ::: "memory");
      __builtin_amdgcn_sched_barrier(0);
      __builtin_amdgcn_s_barrier();   // all tile-kt LDS reads retired block-wide
      __builtin_amdgcn_s_setprio(1);
#pragma unroll
      for (int mf = 0; mf < 4; ++mf)
#pragma unroll
        for (int nf = 0; nf < 4; ++nf)
          acc[mf][nf] = __builtin_amdgcn_mfma_f32_16x16x32_bf16(
              af_[mf], bf_[nf], acc[mf][nf], 0, 0, 0);
      __builtin_amdgcn_s_setprio(0);
    }
  }

  // epilogue: 16x16 C/D layout col=lane&15, row=(lane>>4)*4+reg
#pragma unroll
  for (int mf = 0; mf < 4; ++mf)
#pragma unroll
    for (int nf = 0; nf < 4; ++nf) {
      int col = bn * 256 + wc * 64 + nf * 16 + l16;
      float bv = HAS_BIAS ? bias[col] : 0.f;
#pragma unroll
      for (int r = 0; r < 4; ++r) {
        int row = bm * 256 + wr * 64 + mf * 16 + lq * 4 + r;
        float v = acc[mf][nf][r] + bv;
        if (OUT_BF16)
          ((u16*)Cout)[(size_t)row * N + col] = f2bf(v);
        else
          ((float*)Cout)[(size_t)row * N + col] = v;
      }
    }
}

// ---------------- RoPE in-place on q,k + k-cache write ----------------
__global__ __launch_bounds__(256) void ap_rope(u16* __restrict__ qkv,
                                               const int* __restrict__ pos_list,
                                               const int* __restrict__ slot_mapping,
                                               float* __restrict__ kc) {
  int gid = blockIdx.x * 4 + (threadIdx.x >> 6);
  int i = threadIdx.x & 63;
  int t = gid / 40, head = gid % 40;
  float pos = (float)pos_list[t];
  float inv = expf(-(float)i * 0.14391156516151135f);
  float ang = pos * inv;
  float cs = cosf(ang), sn = sinf(ang);
  int cb = (head < 32) ? head * 128 : 4096 + (head - 32) * 128;
  u16* p = qkv + (size_t)t * QKVW + cb;
  float t1 = bf2f(p[i]), t2 = bf2f(p[i + 64]);
  float o1 = t1 * cs - t2 * sn;
  float o2 = t2 * cs + t1 * sn;
  p[i] = f2bf(o1);
  p[i + 64] = f2bf(o2);
  if (head >= 32) {
    int slot = slot_mapping[t];
    float* kp = kc + (size_t)slot * (NKVH * HDIM) + (head - 32) * 128;
    kp[i] = o1;
    kp[i + 64] = o2;
  }
}

// ---------------- v -> V^T (per b,h) bf16 + v_cache scatter (fused) ----------------
__global__ __launch_bounds__(256) void ap_vtrans2(const u16* __restrict__ qkv,
                                                  const int* __restrict__ slot_mapping,
                                                  float* __restrict__ vc,
                                                  u16* __restrict__ Vt) {
  __shared__ u16 tile[64][68];
  int bid = blockIdx.x;
  int hdt = bid & 1, st = (bid >> 1) & 15, head = bid >> 5;
  int b = head >> 3, h = head & 7;
  int rr = threadIdx.x >> 4, cc = (threadIdx.x & 15) * 4;
#pragma unroll
  for (int i = 0; i < 4; ++i) {
    int s = i * 16 + rr;
    int t = b * 1024 + st * 64 + s;
    u16x4 v = *(const u16x4*)(qkv + (size_t)t * QKVW + 5120 + h * 128 + hdt * 64 + cc);
#pragma unroll
    for (int j = 0; j < 4; ++j) tile[s][cc + j] = v[j];
    int slot = slot_mapping[t];
    f32x4 o;
#pragma unroll
    for (int j = 0; j < 4; ++j) o[j] = bf2f(v[j]);
    *(f32x4*)(vc + (size_t)slot * 1024 + h * 128 + hdt * 64 + cc) = o;
  }
  __syncthreads();
#pragma unroll
  for (int i = 0; i < 4; ++i) {
    int hd = i * 16 + rr;
    u16x4 o;
#pragma unroll
    for (int j = 0; j < 4; ++j) o[j] = tile[cc + j][hd];
    *(u16x4*)(Vt + (size_t)head * (HDIM * SLEN) + (size_t)(hdt * 64 + hd) * SLEN +
              st * 64 + cc) = o;
  }
}

// ---------------- flash attention v7: defer-max + shuffle-free fast path ----------------
__global__ __launch_bounds__(512) void ap_attn7(const u16* __restrict__ qkv,
                                                const u16* __restrict__ Vt,
                                                u16* __restrict__ O) {
  __shared__ u16 sK[64 * 136];      // K tile (kv,hd), stride 136
  __shared__ u16 sV[128 * 72];      // V^T tile (hd,kv), stride 72
  __shared__ u16 sP[8 * 32 * 72];   // per-wave P (q,kv), stride 72
  const int tid = threadIdx.x;
  const int wave = tid >> 6, l = tid & 63, l16 = l & 15, lq = l >> 4;
  const int bid = blockIdx.x;
  const int qt = 15 - (bid & 15);   // heavy blocks first
  const int kvh = (bid >> 4) & 7;
  const int b = bid >> 7;
  const int qh = kvh * 4 + (wave & 3);
  const int q0 = qt * 64 + (wave >> 2) * 32;
  const int head = b * 8 + kvh;
  const float SC2 = 0.12751649736230717f;  // 128^-0.5 * log2(e)

  short8 qf[2][4];
#pragma unroll
  for (int m = 0; m < 2; ++m)
#pragma unroll
    for (int kd = 0; kd < 4; ++kd) {
      size_t t = (size_t)(b * 1024 + q0 + m * 16 + l16);
      qf[m][kd] = *(const short8*)(qkv + t * QKVW + qh * 128 + kd * 32 + lq * 8);
    }

  u16* sPw = sP + wave * 2304;
  f32x4 zv = {0.f, 0.f, 0.f, 0.f};
  f32x4 oacc[2][8];
#pragma unroll
  for (int m = 0; m < 2; ++m)
#pragma unroll
    for (int n = 0; n < 8; ++n) oacc[m][n] = zv;
  float mrun[2][4], lrun[2][4];   // lrun = per-lane partial row sums
#pragma unroll
  for (int m = 0; m < 2; ++m)
#pragma unroll
    for (int r = 0; r < 4; ++r) { mrun[m][r] = -1e30f; lrun[m][r] = 0.f; }

  const int ntiles = qt + 1;
  for (int kt = 0; kt < ntiles; ++kt) {
    const int kv0 = kt * 64;
#pragma unroll
    for (int i = 0; i < 2; ++i) {
      int ci = i * 512 + tid;
      int kr = ci >> 4, ko = (ci & 15) * 8;
      short8 v = *(const short8*)(qkv + (size_t)(b * 1024 + kv0 + kr) * QKVW + 4096 +
                                  kvh * 128 + ko);
      *(short8*)&sK[kr * 136 + ko] = v;
    }
#pragma unroll
    for (int i = 0; i < 2; ++i) {
      int ci = i * 512 + tid;
      int hd = ci >> 3, ko = (ci & 7) * 8;
      short8 v = *(const short8*)(Vt + (size_t)head * (HDIM * SLEN) + (size_t)hd * SLEN +
                                  kv0 + ko);
      *(short8*)&sV[hd * 72 + ko] = v;
    }
    __syncthreads();

    f32x4 sacc[2][4];
#pragma unroll
    for (int m = 0; m < 2; ++m)
#pragma unroll
      for (int nf = 0; nf < 4; ++nf) sacc[m][nf] = zv;
#pragma unroll
    for (int kd = 0; kd < 4; ++kd) {
      short8 kf[4];
#pragma unroll
      for (int nf = 0; nf < 4; ++nf)
        kf[nf] = *(const short8*)&sK[(nf * 16 + l16) * 136 + kd * 32 + lq * 8];
#pragma unroll
      for (int m = 0; m < 2; ++m)
#pragma unroll
        for (int nf = 0; nf < 4; ++nf)
          sacc[m][nf] = __builtin_amdgcn_mfma_f32_16x16x32_bf16(qf[m][kd], kf[nf], sacc[m][nf], 0, 0, 0);
    }
    if (kv0 + 63 > q0) {
#pragma unroll
      for (int m = 0; m < 2; ++m)
#pragma unroll
        for (int nf = 0; nf < 4; ++nf) {
          int kv = kv0 + nf * 16 + l16;
#pragma unroll
          for (int r = 0; r < 4; ++r) {
            int q = q0 + m * 16 + lq * 4 + r;
            if (kv > q) sacc[m][nf][r] = -1e30f;
          }
        }
    }
    // ---- defer-max softmax with shuffle-free fast path ----
    float lmax[2][4];
    bool need = false;
#pragma unroll
    for (int m = 0; m < 2; ++m)
#pragma unroll
      for (int r = 0; r < 4; ++r) {
        lmax[m][r] = fmaxf(fmaxf(sacc[m][0][r], sacc[m][1][r]),
                           fmaxf(sacc[m][2][r], sacc[m][3][r]));
        need = need || ((lmax[m][r] - mrun[m][r]) * SC2 > 8.f);
      }
    if (!__all(!need)) {
#pragma unroll
      for (int m = 0; m < 2; ++m)
#pragma unroll
        for (int r = 0; r < 4; ++r) {
          float mx = lmax[m][r];
#pragma unroll
          for (int off = 8; off; off >>= 1) mx = fmaxf(mx, __shfl_xor(mx, off));
          if ((mx - mrun[m][r]) * SC2 > 8.f) {
            float sc = exp2f((mrun[m][r] - mx) * SC2);
            mrun[m][r] = mx;
            lrun[m][r] *= sc;
#pragma unroll
            for (int n = 0; n < 8; ++n) oacc[m][n][r] *= sc;
          }
        }
    }
#pragma unroll
    for (int m = 0; m < 2; ++m)
#pragma unroll
      for (int r = 0; r < 4; ++r) {
        float mn = mrun[m][r];
        float p0 = exp2f((sacc[m][0][r] - mn) * SC2);
        float p1 = exp2f((sacc[m][1][r] - mn) * SC2);
        float p2 = exp2f((sacc[m][2][r] - mn) * SC2);
        float p3 = exp2f((sacc[m][3][r] - mn) * SC2);
        lrun[m][r] += (p0 + p1) + (p2 + p3);
        int prow = (m * 16 + lq * 4 + r) * 72;
        sPw[prow + l16]      = f2bf(p0);
        sPw[prow + 16 + l16] = f2bf(p1);
        sPw[prow + 32 + l16] = f2bf(p2);
        sPw[prow + 48 + l16] = f2bf(p3);
      }
    short8 pa[2][2];
#pragma unroll
    for (int m = 0; m < 2; ++m)
#pragma unroll
      for (int ks = 0; ks < 2; ++ks)
        pa[m][ks] = *(const short8*)&sPw[(m * 16 + l16) * 72 + ks * 32 + lq * 8];
#pragma unroll
    for (int n = 0; n < 8; ++n) {
#pragma unroll
      for (int ks = 0; ks < 2; ++ks) {
        short8 vb = *(const short8*)&sV[(n * 16 + l16) * 72 + ks * 32 + lq * 8];
#pragma unroll
        for (int m = 0; m < 2; ++m)
          oacc[m][n] = __builtin_amdgcn_mfma_f32_16x16x32_bf16(pa[m][ks], vb, oacc[m][n], 0, 0, 0);
      }
    }
    __syncthreads();
  }
  // epilogue: reduce per-lane lrun partials across the 16-lane group, store
#pragma unroll
  for (int m = 0; m < 2; ++m)
#pragma unroll
    for (int r = 0; r < 4; ++r) {
      float s = lrun[m][r];
#pragma unroll
      for (int off = 8; off; off >>= 1) s += __shfl_xor(s, off);
      float inv = 1.f / s;
      size_t t = (size_t)(b * 1024 + q0 + m * 16 + lq * 4 + r);
#pragma unroll
      for (int n = 0; n < 8; ++n)
        O[t * (size_t)HID + qh * 128 + n * 16 + l16] = f2bf(oacc[m][n][r] * inv);
    }
}

// ---------------- launch ----------------
extern "C" void kernel_launch(void* const* d_in, const int* in_sizes, int n_in,
                              void* d_out, int out_size, void* d_ws, size_t ws_size,
                              hipStream_t stream) {
  const float* x = (const float*)d_in[0];
  const float* wqkv = (const float*)d_in[1];
  const float* bqkv = (const float*)d_in[2];
  const float* wo = (const float*)d_in[3];
  const int* pos_list = (const int*)d_in[4];
  const int* slot_mapping = (const int*)d_in[5];
  const float* k_cache = (const float*)d_in[6];
  const float* v_cache = (const float*)d_in[7];

  float* out = (float*)d_out;
  float* kc = out + (size_t)33554432;
  float* vc = kc + (size_t)16777216;

  char* ws = (char*)d_ws;
  u16* xb    = (u16*)(ws);
  u16* wqkvT = (u16*)(ws + 67108864);
  u16* woT   = (u16*)(ws + 117440512);
  u16* qkvb  = (u16*)(ws + 150994944);
  u16* Vt    = (u16*)(ws + 251658240);
  u16* attnO = xb;

  ap_copy2<<<8192, 256, 0, stream>>>((const f32x4*)k_cache, (f32x4*)kc,
                                     (const f32x4*)v_cache, (f32x4*)vc, 4194304);
  ap_convx<<<16384, 256, 0, stream>>>(x, xb);
  ap_tconv<<<6144, 256, 0, stream>>>(wqkv, wqkvT, 4096, 6144);
  ap_tconv<<<4096, 256, 0, stream>>>(wo, woT, 4096, 4096);
  ap_gemmw<1, 1><<<768, 1024, 0, stream>>>(xb, wqkvT, bqkv, qkvb, 8192, 6144, 4096, 24);
  ap_rope<<<81920, 256, 0, stream>>>(qkvb, pos_list, slot_mapping, kc);
  ap_vtrans2<<<2048, 256, 0, stream>>>(qkvb, slot_mapping, vc, Vt);
  ap_attn7<<<1024, 512, 0, stream>>>(qkvb, Vt, attnO);
  ap_gemmw<0, 0><<<512, 1024, 0, stream>>>(attnO, woT, nullptr, out, 8192, 4096, 4096, 16);
}